// Round 3
// baseline (527.105 us; speedup 1.0000x reference)
//
#include <hip/hip_runtime.h>

typedef unsigned short u16;
typedef unsigned int   u32;
typedef __bf16 bf16x8 __attribute__((ext_vector_type(8)));
typedef float  f32x4  __attribute__((ext_vector_type(4)));

#define S_LEN 4096
#define HIDN  2048
#define NHEAD 16
#define NKVH  4
#define HDIM  128
#define ROTD  64
#define QKVN  3072

__device__ __forceinline__ u16 f2bf(float f) {
  union { float f; u32 u; } v; v.f = f;
  u32 r = v.u + 0x7FFFu + ((v.u >> 16) & 1u);   // RNE
  return (u16)(r >> 16);
}
__device__ __forceinline__ float bf2f(u16 u) {
  union { u32 u; float f; } v; v.u = ((u32)u) << 16; return v.f;
}
__device__ __forceinline__ void gl2lds16(const u16* g, u16* l) {
  __builtin_amdgcn_global_load_lds((const __attribute__((address_space(1))) void*)g,
                                   (__attribute__((address_space(3))) void*)l, 16, 0, 0);
}
__device__ __forceinline__ f32x4 mfma_bf16(bf16x8 a, bf16x8 b, f32x4 c) {
  return __builtin_amdgcn_mfma_f32_16x16x32_bf16(a, b, c, 0, 0, 0);
}

// ---------------- f32 -> bf16 convert (8 elems/thread, exact grid) ----------
__global__ __launch_bounds__(256) void cvt_f32_bf16(const float* __restrict__ in,
                                                    u16* __restrict__ out) {
  size_t i = ((size_t)blockIdx.x * 256 + threadIdx.x) * 8;
  float4 a = *(const float4*)(in + i);
  float4 b = *(const float4*)(in + i + 4);
  uint4 r;
  r.x = (u32)f2bf(a.x) | ((u32)f2bf(a.y) << 16);
  r.y = (u32)f2bf(a.z) | ((u32)f2bf(a.w) << 16);
  r.z = (u32)f2bf(b.x) | ((u32)f2bf(b.y) << 16);
  r.w = (u32)f2bf(b.z) | ((u32)f2bf(b.w) << 16);
  *(uint4*)(out + i) = r;
}

// ---------------- GEMM: C[M,N] = A[M,K] * B[N,K]^T  (bf16 in, f32 acc) ------
// m97 structure: 128x128 tile, BK=64, 4 waves (each 64x64 = 4x4 MFMA frags),
// global_load_lds width 16, single-buffered LDS with 2 barriers per K-step.
template <bool BF16OUT>
__global__ __launch_bounds__(256) void gemm_bt(const u16* __restrict__ A,
                                               const u16* __restrict__ B,
                                               void* __restrict__ Cp,
                                               int M, int N, int K) {
  __shared__ u16 As[128][64];
  __shared__ u16 Bs[128][64];
  const int tid = threadIdx.x;
  const int wave = tid >> 6, lane = tid & 63;
  const int wr = wave >> 1, wc = wave & 1;          // 2x2 wave grid of 64x64
  const int row0 = blockIdx.x * 128, col0 = blockIdx.y * 128;
  const int lr8 = lane >> 3, lc8 = lane & 7;        // staging: 8 rows per 1KB chunk

  f32x4 acc[4][4];
  #pragma unroll
  for (int i = 0; i < 4; ++i)
    #pragma unroll
    for (int j = 0; j < 4; ++j) { f32x4 z = {0.f,0.f,0.f,0.f}; acc[i][j] = z; }

  for (int kt = 0; kt < K; kt += 64) {
    __syncthreads();
    #pragma unroll
    for (int i = 0; i < 4; ++i) {
      int c = wave * 4 + i;                         // chunk 0..15, 8 rows each
      const u16* ga = A + (size_t)(row0 + c*8 + lr8) * K + kt + lc8 * 8;
      gl2lds16(ga, &As[c*8][0]);
      const u16* gb = B + (size_t)(col0 + c*8 + lr8) * K + kt + lc8 * 8;
      gl2lds16(gb, &Bs[c*8][0]);
    }
    __syncthreads();
    #pragma unroll
    for (int ks = 0; ks < 64; ks += 32) {
      bf16x8 af[4], bfr[4];
      #pragma unroll
      for (int mi = 0; mi < 4; ++mi)
        af[mi] = *(const bf16x8*)&As[wr*64 + mi*16 + (lane & 15)][ks + (lane >> 4) * 8];
      #pragma unroll
      for (int ni = 0; ni < 4; ++ni)
        bfr[ni] = *(const bf16x8*)&Bs[wc*64 + ni*16 + (lane & 15)][ks + (lane >> 4) * 8];
      #pragma unroll
      for (int mi = 0; mi < 4; ++mi)
        #pragma unroll
        for (int ni = 0; ni < 4; ++ni)
          acc[mi][ni] = mfma_bf16(af[mi], bfr[ni], acc[mi][ni]);
    }
  }
  // epilogue: C/D layout row=(l>>4)*4+r, col=l&15 (m89-verified)
  const int mw = row0 + wr*64, nw = col0 + wc*64;
  #pragma unroll
  for (int mi = 0; mi < 4; ++mi)
    #pragma unroll
    for (int ni = 0; ni < 4; ++ni)
      #pragma unroll
      for (int r = 0; r < 4; ++r) {
        int m = mw + mi*16 + (lane >> 4) * 4 + r;
        int n = nw + ni*16 + (lane & 15);
        float v = acc[mi][ni][r];
        if (BF16OUT) ((u16*)Cp)[(size_t)m * N + n] = f2bf(v);
        else         ((float*)Cp)[(size_t)m * N + n] = v;
      }
}

// ---------------- fused RMSNorm (full row) + partial RoPE + head transpose --
// qkv: [S][3072] bf16 (q 0..2047 | k 2048..2559 | v untouched here)
// Qo: [NH][S][HD] bf16, Ko: [NKV][S][HD] bf16
__global__ __launch_bounds__(256) void norm_rope(const u16* __restrict__ qkv,
                                                 const float* __restrict__ cosb,
                                                 const float* __restrict__ sinb,
                                                 const float* __restrict__ qw,
                                                 const float* __restrict__ kw,
                                                 u16* __restrict__ Qo,
                                                 u16* __restrict__ Ko) {
  const int s = blockIdx.x, t = threadIdx.x;
  const int wave = t >> 6, lane = t & 63;
  __shared__ float rowbuf[HIDN];
  __shared__ float red[4];
  const u16* base = qkv + (size_t)s * QKVN;

  // ---- Q: 2048 elems, 8/thread ----
  float x[8];
  {
    uint4 v = *(const uint4*)(base + t * 8);
    u32 w4[4] = {v.x, v.y, v.z, v.w};
    #pragma unroll
    for (int j = 0; j < 4; ++j) {
      x[2*j]   = bf2f((u16)(w4[j] & 0xffffu));
      x[2*j+1] = bf2f((u16)(w4[j] >> 16));
    }
  }
  float ss = 0.f;
  #pragma unroll
  for (int j = 0; j < 8; ++j) ss += x[j] * x[j];
  #pragma unroll
  for (int m = 1; m < 64; m <<= 1) ss += __shfl_xor(ss, m);
  if (lane == 0) red[wave] = ss;
  __syncthreads();
  float rs = rsqrtf((red[0]+red[1]+red[2]+red[3]) * (1.0f / HIDN) + 1e-6f);
  #pragma unroll
  for (int j = 0; j < 8; ++j) rowbuf[t*8 + j] = x[j] * rs * qw[t*8 + j];
  __syncthreads();
  {
    int i0 = t * 8, d0 = i0 & (HDIM - 1), hh = i0 >> 7;
    float o[8];
    if (d0 < ROTD) {
      #pragma unroll
      for (int j = 0; j < 8; ++j) {
        int d = d0 + j;
        float rot = (d < 32) ? -rowbuf[i0 + j + 32] : rowbuf[i0 + j - 32];
        o[j] = rowbuf[i0 + j] * cosb[s*ROTD + d] + rot * sinb[s*ROTD + d];
      }
    } else {
      #pragma unroll
      for (int j = 0; j < 8; ++j) o[j] = rowbuf[i0 + j];
    }
    uint4 r;
    r.x = (u32)f2bf(o[0]) | ((u32)f2bf(o[1]) << 16);
    r.y = (u32)f2bf(o[2]) | ((u32)f2bf(o[3]) << 16);
    r.z = (u32)f2bf(o[4]) | ((u32)f2bf(o[5]) << 16);
    r.w = (u32)f2bf(o[6]) | ((u32)f2bf(o[7]) << 16);
    *(uint4*)(Qo + ((size_t)hh * S_LEN + s) * HDIM + d0) = r;
  }

  // ---- K: 512 elems, 2/thread ----
  const u16* kbase = base + HIDN;
  float y0, y1;
  { u32 v = *(const u32*)(kbase + t * 2); y0 = bf2f((u16)(v & 0xffffu)); y1 = bf2f((u16)(v >> 16)); }
  float ss2 = y0*y0 + y1*y1;
  #pragma unroll
  for (int m = 1; m < 64; m <<= 1) ss2 += __shfl_xor(ss2, m);
  __syncthreads();                       // q-phase rowbuf/red reads complete
  if (lane == 0) red[wave] = ss2;
  __syncthreads();
  float rs2 = rsqrtf((red[0]+red[1]+red[2]+red[3]) * (1.0f / 512.0f) + 1e-6f);
  rowbuf[t*2]     = y0 * rs2 * kw[t*2];
  rowbuf[t*2 + 1] = y1 * rs2 * kw[t*2 + 1];
  __syncthreads();
  {
    int i0 = t * 2, d0 = i0 & (HDIM - 1), hh = i0 >> 7;
    float o0, o1;
    if (d0 < ROTD) {
      float r0 = (d0 < 32) ? -rowbuf[i0 + 32] : rowbuf[i0 - 32];
      float r1 = (d0 + 1 < 32) ? -rowbuf[i0 + 1 + 32] : rowbuf[i0 + 1 - 32];
      o0 = rowbuf[i0]     * cosb[s*ROTD + d0]     + r0 * sinb[s*ROTD + d0];
      o1 = rowbuf[i0 + 1] * cosb[s*ROTD + d0 + 1] + r1 * sinb[s*ROTD + d0 + 1];
    } else { o0 = rowbuf[i0]; o1 = rowbuf[i0 + 1]; }
    u32 r = (u32)f2bf(o0) | ((u32)f2bf(o1) << 16);
    *(u32*)(Ko + ((size_t)hh * S_LEN + s) * HDIM + d0) = r;
  }
}

// ---------------- V transpose: qkv[S][3072] v-cols -> Vt[NKV][HD][S] --------
__global__ __launch_bounds__(256) void vtrans(const u16* __restrict__ qkv,
                                              u16* __restrict__ Vt) {
  const int sb = blockIdx.x * 64, db = blockIdx.y * 64, kvh = blockIdx.z;
  __shared__ u16 tile[64][72];
  const int t = threadIdx.x;
  {
    int r = t >> 2, cc = (t & 3) * 16;
    const u16* src = qkv + (size_t)(sb + r) * QKVN + 2560 + kvh * HDIM + db + cc;
    *(uint4*)&tile[r][cc]     = *(const uint4*)(src);
    *(uint4*)&tile[r][cc + 8] = *(const uint4*)(src + 8);
  }
  __syncthreads();
  {
    int d = t >> 2, sc = (t & 3) * 16;
    u16 tmp[16];
    #pragma unroll
    for (int j = 0; j < 16; ++j) tmp[j] = tile[sc + j][d];
    u16* dst = Vt + ((size_t)kvh * HDIM + db + d) * S_LEN + sb + sc;
    *(uint4*)dst       = *(uint4*)&tmp[0];
    *(uint4*)(dst + 8) = *(uint4*)&tmp[8];
  }
}

// ---------------- causal GQA flash attention --------------------------------
// Q [NH][S][HD], K [NKV][S][HD], Vt [NKV][HD][S]  -> O [S][NH*HD] bf16
// block: 4 waves x 16 q-rows = 64 q rows; kv tiles of 64.
// K/V/P LDS XOR-swizzled (byte ^= (row&7)<<4) with pre-swizzled global source.
__global__ __launch_bounds__(256) void attn_fwd(const u16* __restrict__ Q,
                                                const u16* __restrict__ K,
                                                const u16* __restrict__ Vt,
                                                u16* __restrict__ O) {
  const int qb = gridDim.x - 1 - blockIdx.x;      // heavy blocks first
  const int h  = blockIdx.y;
  const int kvh = h >> 2;                          // n_rep = 4
  const int tid = threadIdx.x, wave = tid >> 6, lane = tid & 63;
  __shared__ u16 Ks[64][128];                      // [kv_local][d]   16KB
  __shared__ u16 Vs[128][64];                      // [d][kv_local]   16KB
  __shared__ u16 Ps[4][16][64];                    // per-wave P       8KB

  const float SL = 0.08838834764831845f * 1.4426950408889634f;  // SCALE*log2e
  const float NEG = -1e30f;

  const int qrow = qb * 64 + wave * 16 + (lane & 15);
  bf16x8 qf[4];
  {
    const u16* qptr = Q + ((size_t)h * S_LEN + qrow) * HDIM + (lane >> 4) * 8;
    #pragma unroll
    for (int kk = 0; kk < 4; ++kk) qf[kk] = *(const bf16x8*)(qptr + kk * 32);
  }

  float m2[4] = {NEG, NEG, NEG, NEG};
  float lsum[4] = {0.f, 0.f, 0.f, 0.f};
  f32x4 o[8];
  #pragma unroll
  for (int i = 0; i < 8; ++i) { f32x4 z = {0.f,0.f,0.f,0.f}; o[i] = z; }

  const int qg = qb * 64 + wave * 16 + (lane >> 4) * 4;   // + r = global q row
  const int ntiles = qb + 1;

  for (int kt = 0; kt < ntiles; ++kt) {
    const int kvb = kt * 64;
    __syncthreads();
    // stage K tile: 16 chunks x (4 rows x 256B); source slot pre-swizzled
    #pragma unroll
    for (int i = 0; i < 4; ++i) {
      int cc = wave * 4 + i;
      int r = cc * 4 + (lane >> 4);
      int slot = (lane & 15) ^ (r & 7);
      const u16* g = K + ((size_t)kvh * S_LEN + kvb + r) * HDIM + slot * 8;
      gl2lds16(g, &Ks[cc * 4][0]);
    }
    // stage V tile: 16 chunks x (8 rows x 128B)
    #pragma unroll
    for (int i = 0; i < 4; ++i) {
      int cc = wave * 4 + i;
      int r = cc * 8 + (lane >> 3);
      int slot = (lane & 7) ^ (r & 7);
      const u16* g = Vt + ((size_t)kvh * HDIM + r) * S_LEN + kvb + slot * 8;
      gl2lds16(g, &Vs[cc * 8][0]);
    }
    __syncthreads();

    // QK^T -> sc[nf] (rows=q, cols=kv)
    f32x4 sc[4];
    #pragma unroll
    for (int i = 0; i < 4; ++i) { f32x4 z = {0.f,0.f,0.f,0.f}; sc[i] = z; }
    #pragma unroll
    for (int kk = 0; kk < 4; ++kk)
      #pragma unroll
      for (int nf = 0; nf < 4; ++nf) {
        int r = nf * 16 + (lane & 15);
        int boff = (kk * 64 + (lane >> 4) * 16) ^ ((r & 7) << 4);
        bf16x8 kf = *(const bf16x8*)((const char*)&Ks[r][0] + boff);
        sc[nf] = mfma_bf16(qf[kk], kf, sc[nf]);
      }

    // online softmax (exp2 domain), causal mask
    float pv[4][4];                                  // [nf][r]
    #pragma unroll
    for (int nf = 0; nf < 4; ++nf) {
      int col = kvb + nf * 16 + (lane & 15);
      #pragma unroll
      for (int r = 0; r < 4; ++r)
        pv[nf][r] = (col <= qg + r) ? sc[nf][r] * SL : NEG;
    }
    #pragma unroll
    for (int r = 0; r < 4; ++r) {
      float mx = fmaxf(fmaxf(pv[0][r], pv[1][r]), fmaxf(pv[2][r], pv[3][r]));
      #pragma unroll
      for (int m = 1; m < 16; m <<= 1) mx = fmaxf(mx, __shfl_xor(mx, m));
      float mn = fmaxf(m2[r], mx);
      float cr = exp2f(m2[r] - mn);
      m2[r] = mn;
      float rsum = 0.f;
      #pragma unroll
      for (int nf = 0; nf < 4; ++nf) {
        float e = exp2f(pv[nf][r] - mn);
        pv[nf][r] = e;
        rsum += e;
      }
      #pragma unroll
      for (int m = 1; m < 16; m <<= 1) rsum += __shfl_xor(rsum, m);
      lsum[r] = lsum[r] * cr + rsum;
      #pragma unroll
      for (int nf2 = 0; nf2 < 8; ++nf2) o[nf2][r] *= cr;
    }

    // P -> LDS (swizzled write), then PV
    #pragma unroll
    for (int nf = 0; nf < 4; ++nf)
      #pragma unroll
      for (int r = 0; r < 4; ++r) {
        int prow = (lane >> 4) * 4 + r;
        int bcol = (nf * 32 + (lane & 15) * 2) ^ ((prow & 7) << 4);
        *(u16*)((char*)&Ps[wave][prow][0] + bcol) = f2bf(pv[nf][r]);
      }
    #pragma unroll
    for (int ks = 0; ks < 2; ++ks) {
      int prow = lane & 15;
      int pboff = (ks * 64 + (lane >> 4) * 16) ^ ((prow & 7) << 4);
      bf16x8 pf = *(const bf16x8*)((const char*)&Ps[wave][prow][0] + pboff);
      #pragma unroll
      for (int nf2 = 0; nf2 < 8; ++nf2) {
        int vr = nf2 * 16 + (lane & 15);
        int vboff = (ks * 64 + (lane >> 4) * 16) ^ ((vr & 7) << 4);
        bf16x8 vf = *(const bf16x8*)((const char*)&Vs[vr][0] + vboff);
        o[nf2] = mfma_bf16(pf, vf, o[nf2]);
      }
    }
  }

  // epilogue: O[s][h*128+d]
  #pragma unroll
  for (int r = 0; r < 4; ++r) {
    float inv = 1.f / lsum[r];
    int srow = qg + r;
    #pragma unroll
    for (int nf2 = 0; nf2 < 8; ++nf2) {
      int col = h * HDIM + nf2 * 16 + (lane & 15);
      O[(size_t)srow * HIDN + col] = f2bf(o[nf2][r] * inv);
    }
  }
}

// ---------------- launch -----------------------------------------------------
extern "C" void kernel_launch(void* const* d_in, const int* in_sizes, int n_in,
                              void* d_out, int out_size, void* d_ws, size_t ws_size,
                              hipStream_t stream) {
  (void)in_sizes; (void)n_in; (void)out_size; (void)ws_size;
  const float* h    = (const float*)d_in[0];
  const float* cosb = (const float*)d_in[1];
  const float* sinb = (const float*)d_in[2];
  const float* Wq   = (const float*)d_in[3];
  const float* Wk   = (const float*)d_in[4];
  const float* Wv   = (const float*)d_in[5];
  const float* Wo   = (const float*)d_in[6];
  const float* qw   = (const float*)d_in[7];
  const float* kw   = (const float*)d_in[8];
  float* out = (float*)d_out;

  // workspace layout (64MB total, lifetime-overlapped):
  //  0..16MB : h_bf16, later attn-out bf16
  // 16..20MB : K [NKV][S][HD]
  // 20..24MB : Vt [NKV][HD][S]
  // 24..36MB : Wqkv bf16 (dead after gemm1) -> 24..40MB: Q [NH][S][HD]
  // 40..64MB : qkv bf16 [S][3072] (dead after vtrans) -> 40..48MB: Wo bf16
  char* ws = (char*)d_ws;
  u16* hbf  = (u16*)(ws);
  u16* Kb   = (u16*)(ws + (16u << 20));
  u16* Vtb  = (u16*)(ws + (20u << 20));
  u16* wqkv = (u16*)(ws + (24u << 20));
  u16* Qb   = (u16*)(ws + (24u << 20));
  u16* qkvb = (u16*)(ws + (40u << 20));
  u16* wob  = (u16*)(ws + (40u << 20));

  cvt_f32_bf16<<<4096, 256, 0, stream>>>(h, hbf);                    // 8M
  cvt_f32_bf16<<<2048, 256, 0, stream>>>(Wq, wqkv);                  // 4M
  cvt_f32_bf16<<<512, 256, 0, stream>>>(Wk, wqkv + 4u * 1024 * 1024);
  cvt_f32_bf16<<<512, 256, 0, stream>>>(Wv, wqkv + 5u * 1024 * 1024);

  gemm_bt<true><<<dim3(32, 24), 256, 0, stream>>>(hbf, wqkv, qkvb, 4096, 3072, 2048);

  norm_rope<<<4096, 256, 0, stream>>>(qkvb, cosb, sinb, qw, kw, Qb, Kb);
  vtrans<<<dim3(64, 2, 4), 256, 0, stream>>>(qkvb, Vtb);

  cvt_f32_bf16<<<2048, 256, 0, stream>>>(Wo, wob);                   // qkvb dead now

  attn_fwd<<<dim3(64, 16), 256, 0, stream>>>(Qb, Kb, Vtb, hbf);      // hbf dead after gemm1

  gemm_bt<false><<<dim3(32, 16), 256, 0, stream>>>(hbf, wob, out, 4096, 2048, 2048);
}

// Round 4
// 523.972 us; speedup vs baseline: 1.0060x; 1.0060x over previous
//
#include <hip/hip_runtime.h>

typedef unsigned short u16;
typedef unsigned int   u32;
typedef __bf16 bf16x8 __attribute__((ext_vector_type(8)));
typedef float  f32x4  __attribute__((ext_vector_type(4)));

#define S_LEN 4096
#define HIDN  2048
#define NHEAD 16
#define NKVH  4
#define HDIM  128
#define ROTD  64
#define QKVN  3072

__device__ __forceinline__ u16 f2bf(float f) {
  union { float f; u32 u; } v; v.f = f;
  u32 r = v.u + 0x7FFFu + ((v.u >> 16) & 1u);   // RNE
  return (u16)(r >> 16);
}
__device__ __forceinline__ float bf2f(u16 u) {
  union { u32 u; float f; } v; v.u = ((u32)u) << 16; return v.f;
}
__device__ __forceinline__ void gl2lds16(const u16* g, u16* l) {
  __builtin_amdgcn_global_load_lds((const __attribute__((address_space(1))) void*)g,
                                   (__attribute__((address_space(3))) void*)l, 16, 0, 0);
}
__device__ __forceinline__ f32x4 mfma_bf16(bf16x8 a, bf16x8 b, f32x4 c) {
  return __builtin_amdgcn_mfma_f32_16x16x32_bf16(a, b, c, 0, 0, 0);
}

// ---------------- f32 -> bf16 convert (8 elems/thread, exact grid) ----------
__global__ __launch_bounds__(256) void cvt_f32_bf16(const float* __restrict__ in,
                                                    u16* __restrict__ out) {
  size_t i = ((size_t)blockIdx.x * 256 + threadIdx.x) * 8;
  float4 a = *(const float4*)(in + i);
  float4 b = *(const float4*)(in + i + 4);
  uint4 r;
  r.x = (u32)f2bf(a.x) | ((u32)f2bf(a.y) << 16);
  r.y = (u32)f2bf(a.z) | ((u32)f2bf(a.w) << 16);
  r.z = (u32)f2bf(b.x) | ((u32)f2bf(b.y) << 16);
  r.w = (u32)f2bf(b.z) | ((u32)f2bf(b.w) << 16);
  *(uint4*)(out + i) = r;
}

// ---------------- GEMM: C[M,N] = A[M,K] * B[N,K]^T  (bf16 in, f32 acc) ------
// m97 structure: 128x128 tile, BK=64, 4 waves (each 64x64 = 4x4 MFMA frags),
// global_load_lds width 16, single-buffered LDS with 2 barriers per K-step.
template <bool BF16OUT>
__global__ __launch_bounds__(256) void gemm_bt(const u16* __restrict__ A,
                                               const u16* __restrict__ B,
                                               void* __restrict__ Cp,
                                               int M, int N, int K) {
  __shared__ u16 As[128][64];
  __shared__ u16 Bs[128][64];
  const int tid = threadIdx.x;
  const int wave = tid >> 6, lane = tid & 63;
  const int wr = wave >> 1, wc = wave & 1;          // 2x2 wave grid of 64x64
  const int row0 = blockIdx.x * 128, col0 = blockIdx.y * 128;
  const int lr8 = lane >> 3, lc8 = lane & 7;        // staging: 8 rows per 1KB chunk

  f32x4 acc[4][4];
  #pragma unroll
  for (int i = 0; i < 4; ++i)
    #pragma unroll
    for (int j = 0; j < 4; ++j) { f32x4 z = {0.f,0.f,0.f,0.f}; acc[i][j] = z; }

  for (int kt = 0; kt < K; kt += 64) {
    __syncthreads();
    #pragma unroll
    for (int i = 0; i < 4; ++i) {
      int c = wave * 4 + i;                         // chunk 0..15, 8 rows each
      const u16* ga = A + (size_t)(row0 + c*8 + lr8) * K + kt + lc8 * 8;
      gl2lds16(ga, &As[c*8][0]);
      const u16* gb = B + (size_t)(col0 + c*8 + lr8) * K + kt + lc8 * 8;
      gl2lds16(gb, &Bs[c*8][0]);
    }
    __syncthreads();
    #pragma unroll
    for (int ks = 0; ks < 64; ks += 32) {
      bf16x8 af[4], bfr[4];
      #pragma unroll
      for (int mi = 0; mi < 4; ++mi)
        af[mi] = *(const bf16x8*)&As[wr*64 + mi*16 + (lane & 15)][ks + (lane >> 4) * 8];
      #pragma unroll
      for (int ni = 0; ni < 4; ++ni)
        bfr[ni] = *(const bf16x8*)&Bs[wc*64 + ni*16 + (lane & 15)][ks + (lane >> 4) * 8];
      #pragma unroll
      for (int mi = 0; mi < 4; ++mi)
        #pragma unroll
        for (int ni = 0; ni < 4; ++ni)
          acc[mi][ni] = mfma_bf16(af[mi], bfr[ni], acc[mi][ni]);
    }
  }
  // epilogue: C/D layout row=(l>>4)*4+r, col=l&15 (m89-verified)
  const int mw = row0 + wr*64, nw = col0 + wc*64;
  #pragma unroll
  for (int mi = 0; mi < 4; ++mi)
    #pragma unroll
    for (int ni = 0; ni < 4; ++ni)
      #pragma unroll
      for (int r = 0; r < 4; ++r) {
        int m = mw + mi*16 + (lane >> 4) * 4 + r;
        int n = nw + ni*16 + (lane & 15);
        float v = acc[mi][ni][r];
        if (BF16OUT) ((u16*)Cp)[(size_t)m * N + n] = f2bf(v);
        else         ((float*)Cp)[(size_t)m * N + n] = v;
      }
}

// ---------------- fused RMSNorm (full row) + partial RoPE + head transpose --
// qkv: [S][3072] bf16 (q 0..2047 | k 2048..2559 | v untouched here)
// Qo: [NH][S][HD] bf16, Ko: [NKV][S][HD] bf16
__global__ __launch_bounds__(256) void norm_rope(const u16* __restrict__ qkv,
                                                 const float* __restrict__ cosb,
                                                 const float* __restrict__ sinb,
                                                 const float* __restrict__ qw,
                                                 const float* __restrict__ kw,
                                                 u16* __restrict__ Qo,
                                                 u16* __restrict__ Ko) {
  const int s = blockIdx.x, t = threadIdx.x;
  const int wave = t >> 6, lane = t & 63;
  __shared__ float rowbuf[HIDN];
  __shared__ float red[4];
  const u16* base = qkv + (size_t)s * QKVN;

  // ---- Q: 2048 elems, 8/thread ----
  float x[8];
  {
    uint4 v = *(const uint4*)(base + t * 8);
    u32 w4[4] = {v.x, v.y, v.z, v.w};
    #pragma unroll
    for (int j = 0; j < 4; ++j) {
      x[2*j]   = bf2f((u16)(w4[j] & 0xffffu));
      x[2*j+1] = bf2f((u16)(w4[j] >> 16));
    }
  }
  float ss = 0.f;
  #pragma unroll
  for (int j = 0; j < 8; ++j) ss += x[j] * x[j];
  #pragma unroll
  for (int m = 1; m < 64; m <<= 1) ss += __shfl_xor(ss, m);
  if (lane == 0) red[wave] = ss;
  __syncthreads();
  float rs = rsqrtf((red[0]+red[1]+red[2]+red[3]) * (1.0f / HIDN) + 1e-6f);
  #pragma unroll
  for (int j = 0; j < 8; ++j) rowbuf[t*8 + j] = x[j] * rs * qw[t*8 + j];
  __syncthreads();
  {
    int i0 = t * 8, d0 = i0 & (HDIM - 1), hh = i0 >> 7;
    float o[8];
    if (d0 < ROTD) {
      #pragma unroll
      for (int j = 0; j < 8; ++j) {
        int d = d0 + j;
        float rot = (d < 32) ? -rowbuf[i0 + j + 32] : rowbuf[i0 + j - 32];
        o[j] = rowbuf[i0 + j] * cosb[s*ROTD + d] + rot * sinb[s*ROTD + d];
      }
    } else {
      #pragma unroll
      for (int j = 0; j < 8; ++j) o[j] = rowbuf[i0 + j];
    }
    uint4 r;
    r.x = (u32)f2bf(o[0]) | ((u32)f2bf(o[1]) << 16);
    r.y = (u32)f2bf(o[2]) | ((u32)f2bf(o[3]) << 16);
    r.z = (u32)f2bf(o[4]) | ((u32)f2bf(o[5]) << 16);
    r.w = (u32)f2bf(o[6]) | ((u32)f2bf(o[7]) << 16);
    *(uint4*)(Qo + ((size_t)hh * S_LEN + s) * HDIM + d0) = r;
  }

  // ---- K: 512 elems, 2/thread ----
  const u16* kbase = base + HIDN;
  float y0, y1;
  { u32 v = *(const u32*)(kbase + t * 2); y0 = bf2f((u16)(v & 0xffffu)); y1 = bf2f((u16)(v >> 16)); }
  float ss2 = y0*y0 + y1*y1;
  #pragma unroll
  for (int m = 1; m < 64; m <<= 1) ss2 += __shfl_xor(ss2, m);
  __syncthreads();                       // q-phase rowbuf/red reads complete
  if (lane == 0) red[wave] = ss2;
  __syncthreads();
  float rs2 = rsqrtf((red[0]+red[1]+red[2]+red[3]) * (1.0f / 512.0f) + 1e-6f);
  rowbuf[t*2]     = y0 * rs2 * kw[t*2];
  rowbuf[t*2 + 1] = y1 * rs2 * kw[t*2 + 1];
  __syncthreads();
  {
    int i0 = t * 2, d0 = i0 & (HDIM - 1), hh = i0 >> 7;
    float o0, o1;
    if (d0 < ROTD) {
      float r0 = (d0 < 32) ? -rowbuf[i0 + 32] : rowbuf[i0 - 32];
      float r1 = (d0 + 1 < 32) ? -rowbuf[i0 + 1 + 32] : rowbuf[i0 + 1 - 32];
      o0 = rowbuf[i0]     * cosb[s*ROTD + d0]     + r0 * sinb[s*ROTD + d0];
      o1 = rowbuf[i0 + 1] * cosb[s*ROTD + d0 + 1] + r1 * sinb[s*ROTD + d0 + 1];
    } else { o0 = rowbuf[i0]; o1 = rowbuf[i0 + 1]; }
    u32 r = (u32)f2bf(o0) | ((u32)f2bf(o1) << 16);
    *(u32*)(Ko + ((size_t)hh * S_LEN + s) * HDIM + d0) = r;
  }
}

// ---------------- V transpose: qkv[S][3072] v-cols -> Vt[NKV][HD][S] --------
__global__ __launch_bounds__(256) void vtrans(const u16* __restrict__ qkv,
                                              u16* __restrict__ Vt) {
  const int sb = blockIdx.x * 64, db = blockIdx.y * 64, kvh = blockIdx.z;
  __shared__ u16 tile[64][72];
  const int t = threadIdx.x;
  {
    int r = t >> 2, cc = (t & 3) * 16;
    const u16* src = qkv + (size_t)(sb + r) * QKVN + 2560 + kvh * HDIM + db + cc;
    *(uint4*)&tile[r][cc]     = *(const uint4*)(src);
    *(uint4*)&tile[r][cc + 8] = *(const uint4*)(src + 8);
  }
  __syncthreads();
  {
    int d = t >> 2, sc = (t & 3) * 16;
    u16 tmp[16];
    #pragma unroll
    for (int j = 0; j < 16; ++j) tmp[j] = tile[sc + j][d];
    u16* dst = Vt + ((size_t)kvh * HDIM + db + d) * S_LEN + sb + sc;
    *(uint4*)dst       = *(uint4*)&tmp[0];
    *(uint4*)(dst + 8) = *(uint4*)&tmp[8];
  }
}

// ---------------- causal GQA flash attention --------------------------------
// Q [NH][S][HD], K [NKV][S][HD], Vt [NKV][HD][S]  -> O [S][NH*HD] bf16
// block: 4 waves x 16 q-rows = 64 q rows; kv tiles of 64.
// K/V/P LDS XOR-swizzled (byte ^= (row&7)<<4) with pre-swizzled global source.
__global__ __launch_bounds__(256) void attn_fwd(const u16* __restrict__ Q,
                                                const u16* __restrict__ K,
                                                const u16* __restrict__ Vt,
                                                u16* __restrict__ O) {
  const int qb = gridDim.x - 1 - blockIdx.x;      // heavy blocks first
  const int h  = blockIdx.y;
  const int kvh = h >> 2;                          // n_rep = 4
  const int tid = threadIdx.x, wave = tid >> 6, lane = tid & 63;
  __shared__ u16 Ks[64][128];                      // [kv_local][d]   16KB
  __shared__ u16 Vs[128][64];                      // [d][kv_local]   16KB
  __shared__ u16 Ps[4][16][64];                    // per-wave P       8KB

  const float SL = 0.08838834764831845f * 1.4426950408889634f;  // SCALE*log2e
  const float NEG = -1e30f;

  const int qrow = qb * 64 + wave * 16 + (lane & 15);
  bf16x8 qf[4];
  {
    const u16* qptr = Q + ((size_t)h * S_LEN + qrow) * HDIM + (lane >> 4) * 8;
    #pragma unroll
    for (int kk = 0; kk < 4; ++kk) qf[kk] = *(const bf16x8*)(qptr + kk * 32);
  }

  float m2[4] = {NEG, NEG, NEG, NEG};
  float lsum[4] = {0.f, 0.f, 0.f, 0.f};
  f32x4 o[8];
  #pragma unroll
  for (int i = 0; i < 8; ++i) { f32x4 z = {0.f,0.f,0.f,0.f}; o[i] = z; }

  const int qg = qb * 64 + wave * 16 + (lane >> 4) * 4;   // + r = global q row
  const int ntiles = qb + 1;

  for (int kt = 0; kt < ntiles; ++kt) {
    const int kvb = kt * 64;
    __syncthreads();
    // stage K tile: 16 chunks x (4 rows x 256B); source slot pre-swizzled
    #pragma unroll
    for (int i = 0; i < 4; ++i) {
      int cc = wave * 4 + i;
      int r = cc * 4 + (lane >> 4);
      int slot = (lane & 15) ^ (r & 7);
      const u16* g = K + ((size_t)kvh * S_LEN + kvb + r) * HDIM + slot * 8;
      gl2lds16(g, &Ks[cc * 4][0]);
    }
    // stage V tile: 16 chunks x (8 rows x 128B)
    #pragma unroll
    for (int i = 0; i < 4; ++i) {
      int cc = wave * 4 + i;
      int r = cc * 8 + (lane >> 3);
      int slot = (lane & 7) ^ (r & 7);
      const u16* g = Vt + ((size_t)kvh * HDIM + r) * S_LEN + kvb + slot * 8;
      gl2lds16(g, &Vs[cc * 8][0]);
    }
    __syncthreads();

    // QK^T -> sc[nf] (rows=q, cols=kv)
    f32x4 sc[4];
    #pragma unroll
    for (int i = 0; i < 4; ++i) { f32x4 z = {0.f,0.f,0.f,0.f}; sc[i] = z; }
    #pragma unroll
    for (int kk = 0; kk < 4; ++kk)
      #pragma unroll
      for (int nf = 0; nf < 4; ++nf) {
        int r = nf * 16 + (lane & 15);
        int boff = (kk * 64 + (lane >> 4) * 16) ^ ((r & 7) << 4);
        bf16x8 kf = *(const bf16x8*)((const char*)&Ks[r][0] + boff);
        sc[nf] = mfma_bf16(qf[kk], kf, sc[nf]);
      }

    // online softmax (exp2 domain), causal mask
    float pv[4][4];                                  // [nf][r]
    #pragma unroll
    for (int nf = 0; nf < 4; ++nf) {
      int col = kvb + nf * 16 + (lane & 15);
      #pragma unroll
      for (int r = 0; r < 4; ++r)
        pv[nf][r] = (col <= qg + r) ? sc[nf][r] * SL : NEG;
    }
    #pragma unroll
    for (int r = 0; r < 4; ++r) {
      float mx = fmaxf(fmaxf(pv[0][r], pv[1][r]), fmaxf(pv[2][r], pv[3][r]));
      #pragma unroll
      for (int m = 1; m < 16; m <<= 1) mx = fmaxf(mx, __shfl_xor(mx, m));
      float mn = fmaxf(m2[r], mx);
      float cr = exp2f(m2[r] - mn);
      m2[r] = mn;
      float rsum = 0.f;
      #pragma unroll
      for (int nf = 0; nf < 4; ++nf) {
        float e = exp2f(pv[nf][r] - mn);
        pv[nf][r] = e;
        rsum += e;
      }
      #pragma unroll
      for (int m = 1; m < 16; m <<= 1) rsum += __shfl_xor(rsum, m);
      lsum[r] = lsum[r] * cr + rsum;
      #pragma unroll
      for (int nf2 = 0; nf2 < 8; ++nf2) o[nf2][r] *= cr;
    }

    // P -> LDS (swizzled write), then PV
    #pragma unroll
    for (int nf = 0; nf < 4; ++nf)
      #pragma unroll
      for (int r = 0; r < 4; ++r) {
        int prow = (lane >> 4) * 4 + r;
        int bcol = (nf * 32 + (lane & 15) * 2) ^ ((prow & 7) << 4);
        *(u16*)((char*)&Ps[wave][prow][0] + bcol) = f2bf(pv[nf][r]);
      }
    #pragma unroll
    for (int ks = 0; ks < 2; ++ks) {
      int prow = lane & 15;
      int pboff = (ks * 64 + (lane >> 4) * 16) ^ ((prow & 7) << 4);
      bf16x8 pf = *(const bf16x8*)((const char*)&Ps[wave][prow][0] + pboff);
      #pragma unroll
      for (int nf2 = 0; nf2 < 8; ++nf2) {
        int vr = nf2 * 16 + (lane & 15);
        int vboff = (ks * 64 + (lane >> 4) * 16) ^ ((vr & 7) << 4);
        bf16x8 vf = *(const bf16x8*)((const char*)&Vs[vr][0] + vboff);
        o[nf2] = mfma_bf16(pf, vf, o[nf2]);
      }
    }
  }

  // epilogue: O[s][h*128+d]
  #pragma unroll
  for (int r = 0; r < 4; ++r) {
    float inv = 1.f / lsum[r];
    int srow = qg + r;
    #pragma unroll
    for (int nf2 = 0; nf2 < 8; ++nf2) {
      int col = h * HDIM + nf2 * 16 + (lane & 15);
      O[(size_t)srow * HIDN + col] = f2bf(o[nf2][r] * inv);
    }
  }
}

// ---------------- launch -----------------------------------------------------
extern "C" void kernel_launch(void* const* d_in, const int* in_sizes, int n_in,
                              void* d_out, int out_size, void* d_ws, size_t ws_size,
                              hipStream_t stream) {
  (void)in_sizes; (void)n_in; (void)out_size; (void)ws_size;
  const float* h    = (const float*)d_in[0];
  const float* cosb = (const float*)d_in[1];
  const float* sinb = (const float*)d_in[2];
  const float* Wq   = (const float*)d_in[3];
  const float* Wk   = (const float*)d_in[4];
  const float* Wv   = (const float*)d_in[5];
  const float* Wo   = (const float*)d_in[6];
  const float* qw   = (const float*)d_in[7];
  const float* kw   = (const float*)d_in[8];
  float* out = (float*)d_out;

  // workspace layout (64MB total, lifetime-overlapped):
  //  0..16MB : h_bf16, later attn-out bf16
  // 16..20MB : K [NKV][S][HD]
  // 20..24MB : Vt [NKV][HD][S]
  // 24..36MB : Wqkv bf16 (dead after gemm1) -> 24..40MB: Q [NH][S][HD]
  // 40..64MB : qkv bf16 [S][3072] (dead after vtrans) -> 40..48MB: Wo bf16
  char* ws = (char*)d_ws;
  u16* hbf  = (u16*)(ws);
  u16* Kb   = (u16*)(ws + (16u << 20));
  u16* Vtb  = (u16*)(ws + (20u << 20));
  u16* wqkv = (u16*)(ws + (24u << 20));
  u16* Qb   = (u16*)(ws + (24u << 20));
  u16* qkvb = (u16*)(ws + (40u << 20));
  u16* wob  = (u16*)(ws + (40u << 20));

  cvt_f32_bf16<<<4096, 256, 0, stream>>>(h, hbf);                    // 8M
  cvt_f32_bf16<<<2048, 256, 0, stream>>>(Wq, wqkv);                  // 4M
  cvt_f32_bf16<<<512, 256, 0, stream>>>(Wk, wqkv + 4u * 1024 * 1024);
  cvt_f32_bf16<<<512, 256, 0, stream>>>(Wv, wqkv + 5u * 1024 * 1024);

  gemm_bt<true><<<dim3(32, 24), 256, 0, stream>>>(hbf, wqkv, qkvb, 4096, 3072, 2048);

  norm_rope<<<4096, 256, 0, stream>>>(qkvb, cosb, sinb, qw, kw, Qb, Kb);
  vtrans<<<dim3(64, 2, 4), 256, 0, stream>>>(qkvb, Vtb);

  cvt_f32_bf16<<<2048, 256, 0, stream>>>(Wo, wob);                   // qkvb dead now

  attn_fwd<<<dim3(64, 16), 256, 0, stream>>>(Qb, Kb, Vtb, hbf);      // hbf dead after gemm1

  gemm_bt<false><<<dim3(32, 16), 256, 0, stream>>>(hbf, wob, out, 4096, 2048, 2048);
}

// Round 5
// 343.733 us; speedup vs baseline: 1.5335x; 1.5244x over previous
//
#include <hip/hip_runtime.h>

typedef unsigned short u16;
typedef unsigned int   u32;
typedef __bf16 bf16x8 __attribute__((ext_vector_type(8)));
typedef float  f32x4  __attribute__((ext_vector_type(4)));

#define S_LEN 4096
#define HIDN  2048
#define NHEAD 16
#define NKVH  4
#define HDIM  128
#define ROTD  64
#define QKVN  3072

__device__ __forceinline__ u16 f2bf(float f) {
  union { float f; u32 u; } v; v.f = f;
  u32 r = v.u + 0x7FFFu + ((v.u >> 16) & 1u);   // RNE
  return (u16)(r >> 16);
}
__device__ __forceinline__ float bf2f(u16 u) {
  union { u32 u; float f; } v; v.u = ((u32)u) << 16; return v.f;
}
__device__ __forceinline__ void gl2lds16(const u16* g, u16* l) {
  __builtin_amdgcn_global_load_lds((const __attribute__((address_space(1))) void*)g,
                                   (__attribute__((address_space(3))) void*)l, 16, 0, 0);
}
__device__ __forceinline__ f32x4 mfma_bf16(bf16x8 a, bf16x8 b, f32x4 c) {
  return __builtin_amdgcn_mfma_f32_16x16x32_bf16(a, b, c, 0, 0, 0);
}

// ---------------- f32 -> bf16 convert (8 elems/thread, exact grid) ----------
__global__ __launch_bounds__(256) void cvt_f32_bf16(const float* __restrict__ in,
                                                    u16* __restrict__ out) {
  size_t i = ((size_t)blockIdx.x * 256 + threadIdx.x) * 8;
  float4 a = *(const float4*)(in + i);
  float4 b = *(const float4*)(in + i + 4);
  uint4 r;
  r.x = (u32)f2bf(a.x) | ((u32)f2bf(a.y) << 16);
  r.y = (u32)f2bf(a.z) | ((u32)f2bf(a.w) << 16);
  r.z = (u32)f2bf(b.x) | ((u32)f2bf(b.y) << 16);
  r.w = (u32)f2bf(b.z) | ((u32)f2bf(b.w) << 16);
  *(uint4*)(out + i) = r;
}

// ---------------- GEMM: C[M,N] = A[M,K] * B[N,K]^T  (bf16 in, f32 acc) ------
// m97 structure: 128x128 tile, BK=64, 4 waves (each 64x64 = 4x4 MFMA frags),
// global_load_lds width 16, single-buffered LDS with 2 barriers per K-step.
template <bool BF16OUT>
__global__ __launch_bounds__(256) void gemm_bt(const u16* __restrict__ A,
                                               const u16* __restrict__ B,
                                               void* __restrict__ Cp,
                                               int M, int N, int K) {
  __shared__ u16 As[128][64];
  __shared__ u16 Bs[128][64];
  const int tid = threadIdx.x;
  const int wave = tid >> 6, lane = tid & 63;
  const int wr = wave >> 1, wc = wave & 1;          // 2x2 wave grid of 64x64
  const int row0 = blockIdx.x * 128, col0 = blockIdx.y * 128;
  const int lr8 = lane >> 3, lc8 = lane & 7;        // staging: 8 rows per 1KB chunk

  f32x4 acc[4][4];
  #pragma unroll
  for (int i = 0; i < 4; ++i)
    #pragma unroll
    for (int j = 0; j < 4; ++j) { f32x4 z = {0.f,0.f,0.f,0.f}; acc[i][j] = z; }

  for (int kt = 0; kt < K; kt += 64) {
    __syncthreads();
    #pragma unroll
    for (int i = 0; i < 4; ++i) {
      int c = wave * 4 + i;                         // chunk 0..15, 8 rows each
      const u16* ga = A + (size_t)(row0 + c*8 + lr8) * K + kt + lc8 * 8;
      gl2lds16(ga, &As[c*8][0]);
      const u16* gb = B + (size_t)(col0 + c*8 + lr8) * K + kt + lc8 * 8;
      gl2lds16(gb, &Bs[c*8][0]);
    }
    __syncthreads();
    #pragma unroll
    for (int ks = 0; ks < 64; ks += 32) {
      bf16x8 af[4], bfr[4];
      #pragma unroll
      for (int mi = 0; mi < 4; ++mi)
        af[mi] = *(const bf16x8*)&As[wr*64 + mi*16 + (lane & 15)][ks + (lane >> 4) * 8];
      #pragma unroll
      for (int ni = 0; ni < 4; ++ni)
        bfr[ni] = *(const bf16x8*)&Bs[wc*64 + ni*16 + (lane & 15)][ks + (lane >> 4) * 8];
      #pragma unroll
      for (int mi = 0; mi < 4; ++mi)
        #pragma unroll
        for (int ni = 0; ni < 4; ++ni)
          acc[mi][ni] = mfma_bf16(af[mi], bfr[ni], acc[mi][ni]);
    }
  }
  // epilogue: C/D layout row=(l>>4)*4+r, col=l&15 (m89-verified)
  const int mw = row0 + wr*64, nw = col0 + wc*64;
  #pragma unroll
  for (int mi = 0; mi < 4; ++mi)
    #pragma unroll
    for (int ni = 0; ni < 4; ++ni)
      #pragma unroll
      for (int r = 0; r < 4; ++r) {
        int m = mw + mi*16 + (lane >> 4) * 4 + r;
        int n = nw + ni*16 + (lane & 15);
        float v = acc[mi][ni][r];
        if (BF16OUT) ((u16*)Cp)[(size_t)m * N + n] = f2bf(v);
        else         ((float*)Cp)[(size_t)m * N + n] = v;
      }
}

// ---------------- fused RMSNorm (full row) + partial RoPE + head transpose --
__global__ __launch_bounds__(256) void norm_rope(const u16* __restrict__ qkv,
                                                 const float* __restrict__ cosb,
                                                 const float* __restrict__ sinb,
                                                 const float* __restrict__ qw,
                                                 const float* __restrict__ kw,
                                                 u16* __restrict__ Qo,
                                                 u16* __restrict__ Ko) {
  const int s = blockIdx.x, t = threadIdx.x;
  const int wave = t >> 6, lane = t & 63;
  __shared__ float rowbuf[HIDN];
  __shared__ float red[4];
  const u16* base = qkv + (size_t)s * QKVN;

  // ---- Q: 2048 elems, 8/thread ----
  float x[8];
  {
    uint4 v = *(const uint4*)(base + t * 8);
    u32 w4[4] = {v.x, v.y, v.z, v.w};
    #pragma unroll
    for (int j = 0; j < 4; ++j) {
      x[2*j]   = bf2f((u16)(w4[j] & 0xffffu));
      x[2*j+1] = bf2f((u16)(w4[j] >> 16));
    }
  }
  float ss = 0.f;
  #pragma unroll
  for (int j = 0; j < 8; ++j) ss += x[j] * x[j];
  #pragma unroll
  for (int m = 1; m < 64; m <<= 1) ss += __shfl_xor(ss, m);
  if (lane == 0) red[wave] = ss;
  __syncthreads();
  float rs = rsqrtf((red[0]+red[1]+red[2]+red[3]) * (1.0f / HIDN) + 1e-6f);
  #pragma unroll
  for (int j = 0; j < 8; ++j) rowbuf[t*8 + j] = x[j] * rs * qw[t*8 + j];
  __syncthreads();
  {
    int i0 = t * 8, d0 = i0 & (HDIM - 1), hh = i0 >> 7;
    float o[8];
    if (d0 < ROTD) {
      #pragma unroll
      for (int j = 0; j < 8; ++j) {
        int d = d0 + j;
        float rot = (d < 32) ? -rowbuf[i0 + j + 32] : rowbuf[i0 + j - 32];
        o[j] = rowbuf[i0 + j] * cosb[s*ROTD + d] + rot * sinb[s*ROTD + d];
      }
    } else {
      #pragma unroll
      for (int j = 0; j < 8; ++j) o[j] = rowbuf[i0 + j];
    }
    uint4 r;
    r.x = (u32)f2bf(o[0]) | ((u32)f2bf(o[1]) << 16);
    r.y = (u32)f2bf(o[2]) | ((u32)f2bf(o[3]) << 16);
    r.z = (u32)f2bf(o[4]) | ((u32)f2bf(o[5]) << 16);
    r.w = (u32)f2bf(o[6]) | ((u32)f2bf(o[7]) << 16);
    *(uint4*)(Qo + ((size_t)hh * S_LEN + s) * HDIM + d0) = r;
  }

  // ---- K: 512 elems, 2/thread ----
  const u16* kbase = base + HIDN;
  float y0, y1;
  { u32 v = *(const u32*)(kbase + t * 2); y0 = bf2f((u16)(v & 0xffffu)); y1 = bf2f((u16)(v >> 16)); }
  float ss2 = y0*y0 + y1*y1;
  #pragma unroll
  for (int m = 1; m < 64; m <<= 1) ss2 += __shfl_xor(ss2, m);
  __syncthreads();                       // q-phase rowbuf/red reads complete
  if (lane == 0) red[wave] = ss2;
  __syncthreads();
  float rs2 = rsqrtf((red[0]+red[1]+red[2]+red[3]) * (1.0f / 512.0f) + 1e-6f);
  rowbuf[t*2]     = y0 * rs2 * kw[t*2];
  rowbuf[t*2 + 1] = y1 * rs2 * kw[t*2 + 1];
  __syncthreads();
  {
    int i0 = t * 2, d0 = i0 & (HDIM - 1), hh = i0 >> 7;
    float o0, o1;
    if (d0 < ROTD) {
      float r0 = (d0 < 32) ? -rowbuf[i0 + 32] : rowbuf[i0 - 32];
      float r1 = (d0 + 1 < 32) ? -rowbuf[i0 + 1 + 32] : rowbuf[i0 + 1 - 32];
      o0 = rowbuf[i0]     * cosb[s*ROTD + d0]     + r0 * sinb[s*ROTD + d0];
      o1 = rowbuf[i0 + 1] * cosb[s*ROTD + d0 + 1] + r1 * sinb[s*ROTD + d0 + 1];
    } else { o0 = rowbuf[i0]; o1 = rowbuf[i0 + 1]; }
    u32 r = (u32)f2bf(o0) | ((u32)f2bf(o1) << 16);
    *(u32*)(Ko + ((size_t)hh * S_LEN + s) * HDIM + d0) = r;
  }
}

// ---------------- V transpose: qkv[S][3072] v-cols -> Vt[NKV][HD][S] --------
__global__ __launch_bounds__(256) void vtrans(const u16* __restrict__ qkv,
                                              u16* __restrict__ Vt) {
  const int sb = blockIdx.x * 64, db = blockIdx.y * 64, kvh = blockIdx.z;
  __shared__ u16 tile[64][72];
  const int t = threadIdx.x;
  {
    int r = t >> 2, cc = (t & 3) * 16;
    const u16* src = qkv + (size_t)(sb + r) * QKVN + 2560 + kvh * HDIM + db + cc;
    *(uint4*)&tile[r][cc]     = *(const uint4*)(src);
    *(uint4*)&tile[r][cc + 8] = *(const uint4*)(src + 8);
  }
  __syncthreads();
  {
    int d = t >> 2, sc = (t & 3) * 16;
    u16 tmp[16];
    #pragma unroll
    for (int j = 0; j < 16; ++j) tmp[j] = tile[sc + j][d];
    u16* dst = Vt + ((size_t)kvh * HDIM + db + d) * S_LEN + sb + sc;
    *(uint4*)dst       = *(uint4*)&tmp[0];
    *(uint4*)(dst + 8) = *(uint4*)&tmp[8];
  }
}

// ---------------- causal GQA flash attention (v2) ---------------------------
// Q [NH][S][HD], K [NKV][S][HD], Vt [NKV][HD][S]  -> O [S][NH*HD] bf16
// Mirror-paired blocks: block p handles qb=p then qb=63-p -> 65 tiles each.
// Grid 32x16 = 512 blocks, 72KB LDS -> 2 blocks/CU, all resident, no tail.
// 2-phase prefetch: stage(next) issued before compute(cur); one barrier/tile.
// Diagonal-only causal mask; defer-max (T13, THR=8 in exp2 domain);
// lane-local lsum (reduced once in epilogue); setprio around MFMA (T5).
__global__ __launch_bounds__(256) void attn_fwd(const u16* __restrict__ Q,
                                                const u16* __restrict__ K,
                                                const u16* __restrict__ Vt,
                                                u16* __restrict__ O) {
  const int p   = blockIdx.x;                      // pair index 0..31
  const int h   = blockIdx.y;
  const int kvh = h >> 2;                          // n_rep = 4
  const int tid = threadIdx.x, wave = tid >> 6, lane = tid & 63;
  __shared__ u16 Ks[2][64][128];                   // [buf][kv][d]   32KB
  __shared__ u16 Vs[2][128][64];                   // [buf][d][kv]   32KB
  __shared__ u16 Ps[4][16][64];                    // per-wave P      8KB

  const float SL  = 0.08838834764831845f * 1.4426950408889634f;  // SCALE*log2e
  const float NEG = -1e30f;
  const float THR = 8.0f;                          // defer-max threshold (exp2 dom)

  auto stage = [&](int buf, int kvb) {
    #pragma unroll
    for (int i = 0; i < 4; ++i) {                  // K: 16 chunks x 4 rows x 256B
      int cc = wave * 4 + i;
      int r = cc * 4 + (lane >> 4);
      int slot = (lane & 15) ^ (r & 7);
      gl2lds16(K + ((size_t)kvh * S_LEN + kvb + r) * HDIM + slot * 8,
               &Ks[buf][cc * 4][0]);
    }
    #pragma unroll
    for (int i = 0; i < 4; ++i) {                  // V: 16 chunks x 8 rows x 128B
      int cc = wave * 4 + i;
      int r = cc * 8 + (lane >> 3);
      int slot = (lane & 7) ^ (r & 7);
      gl2lds16(Vt + ((size_t)kvh * HDIM + r) * S_LEN + kvb + slot * 8,
               &Vs[buf][cc * 8][0]);
    }
  };

  int cur = 0;
  stage(0, 0);                                     // prologue: job0 tile0
  __syncthreads();

  for (int job = 0; job < 2; ++job) {
    const int qb = job ? (63 - p) : p;
    const int ntiles = qb + 1;
    const int qrow = qb * 64 + wave * 16 + (lane & 15);
    const int qg   = qb * 64 + wave * 16 + (lane >> 4) * 4;   // + r = global q row

    bf16x8 qf[4];
    {
      const u16* qptr = Q + ((size_t)h * S_LEN + qrow) * HDIM + (lane >> 4) * 8;
      #pragma unroll
      for (int kk = 0; kk < 4; ++kk) qf[kk] = *(const bf16x8*)(qptr + kk * 32);
    }

    float m2[4]   = {NEG, NEG, NEG, NEG};
    float lsum[4] = {0.f, 0.f, 0.f, 0.f};          // lane-local partial sums
    f32x4 o[8];
    #pragma unroll
    for (int i = 0; i < 8; ++i) { f32x4 z = {0.f,0.f,0.f,0.f}; o[i] = z; }

    for (int kt = 0; kt < ntiles; ++kt) {
      // ---- prefetch next tile (this job's kt+1, or next job's tile 0) ----
      if (kt + 1 < ntiles)      stage(cur ^ 1, (kt + 1) * 64);
      else if (job == 0)        stage(cur ^ 1, 0);

      // ---- QK^T from Ks[cur] ----
      f32x4 sc[4];
      #pragma unroll
      for (int i = 0; i < 4; ++i) { f32x4 z = {0.f,0.f,0.f,0.f}; sc[i] = z; }
      __builtin_amdgcn_s_setprio(1);
      #pragma unroll
      for (int kk = 0; kk < 4; ++kk)
        #pragma unroll
        for (int nf = 0; nf < 4; ++nf) {
          int r = nf * 16 + (lane & 15);
          int boff = (kk * 64 + (lane >> 4) * 16) ^ ((r & 7) << 4);
          bf16x8 kf = *(const bf16x8*)((const char*)&Ks[cur][r][0] + boff);
          sc[nf] = mfma_bf16(qf[kk], kf, sc[nf]);
        }
      __builtin_amdgcn_s_setprio(0);

      // ---- softmax (exp2 domain); mask only on the diagonal tile ----
      const int kvb = kt * 64;
      float pv[4][4];                              // [nf][r]
      if (kt == ntiles - 1) {                      // diagonal tile (wave-uniform)
        #pragma unroll
        for (int nf = 0; nf < 4; ++nf) {
          int col = kvb + nf * 16 + (lane & 15);
          #pragma unroll
          for (int r = 0; r < 4; ++r)
            pv[nf][r] = (col <= qg + r) ? sc[nf][r] * SL : NEG;
        }
      } else {
        #pragma unroll
        for (int nf = 0; nf < 4; ++nf)
          #pragma unroll
          for (int r = 0; r < 4; ++r)
            pv[nf][r] = sc[nf][r] * SL;
      }

      float pm[4];
      #pragma unroll
      for (int r = 0; r < 4; ++r) {
        float mx = fmaxf(fmaxf(pv[0][r], pv[1][r]), fmaxf(pv[2][r], pv[3][r]));
        #pragma unroll
        for (int m = 1; m < 16; m <<= 1) mx = fmaxf(mx, __shfl_xor(mx, m));
        pm[r] = mx;
      }
      // defer-max: rescale only when a row max grew past THR (wave-uniform)
      bool grow = (pm[0] > m2[0] + THR) | (pm[1] > m2[1] + THR) |
                  (pm[2] > m2[2] + THR) | (pm[3] > m2[3] + THR);
      if (__any(grow)) {
        #pragma unroll
        for (int r = 0; r < 4; ++r) {
          float mn = fmaxf(m2[r], pm[r]);
          float cr = exp2f(m2[r] - mn);
          m2[r] = mn;
          lsum[r] *= cr;
          #pragma unroll
          for (int nf2 = 0; nf2 < 8; ++nf2) o[nf2][r] *= cr;
        }
      }
      #pragma unroll
      for (int r = 0; r < 4; ++r) {
        #pragma unroll
        for (int nf = 0; nf < 4; ++nf) pv[nf][r] = exp2f(pv[nf][r] - m2[r]);
        lsum[r] += pv[0][r] + pv[1][r] + pv[2][r] + pv[3][r];
      }

      // ---- P -> LDS (swizzled), then PV from Vs[cur] ----
      #pragma unroll
      for (int nf = 0; nf < 4; ++nf)
        #pragma unroll
        for (int r = 0; r < 4; ++r) {
          int prow = (lane >> 4) * 4 + r;
          int bcol = (nf * 32 + (lane & 15) * 2) ^ ((prow & 7) << 4);
          *(u16*)((char*)&Ps[wave][prow][0] + bcol) = f2bf(pv[nf][r]);
        }
      __builtin_amdgcn_s_setprio(1);
      #pragma unroll
      for (int ks = 0; ks < 2; ++ks) {
        int prow = lane & 15;
        int pboff = (ks * 64 + (lane >> 4) * 16) ^ ((prow & 7) << 4);
        bf16x8 pf = *(const bf16x8*)((const char*)&Ps[wave][prow][0] + pboff);
        #pragma unroll
        for (int nf2 = 0; nf2 < 8; ++nf2) {
          int vr = nf2 * 16 + (lane & 15);
          int vboff = (ks * 64 + (lane >> 4) * 16) ^ ((vr & 7) << 4);
          bf16x8 vf = *(const bf16x8*)((const char*)&Vs[cur][vr][0] + vboff);
          o[nf2] = mfma_bf16(pf, vf, o[nf2]);
        }
      }
      __builtin_amdgcn_s_setprio(0);

      __syncthreads();                             // vmcnt(0)+barrier: next buf ready,
      cur ^= 1;                                    // cur buf safe to overwrite
    }

    // ---- epilogue: reduce lane-local lsum across the 16-lane row group ----
    #pragma unroll
    for (int r = 0; r < 4; ++r) {
      float lt = lsum[r];
      #pragma unroll
      for (int m = 1; m < 16; m <<= 1) lt += __shfl_xor(lt, m);
      float inv = 1.f / lt;
      int srow = qg + r;
      #pragma unroll
      for (int nf2 = 0; nf2 < 8; ++nf2) {
        int col = h * HDIM + nf2 * 16 + (lane & 15);
        O[(size_t)srow * HIDN + col] = f2bf(o[nf2][r] * inv);
      }
    }
  }
}

// ---------------- launch -----------------------------------------------------
extern "C" void kernel_launch(void* const* d_in, const int* in_sizes, int n_in,
                              void* d_out, int out_size, void* d_ws, size_t ws_size,
                              hipStream_t stream) {
  (void)in_sizes; (void)n_in; (void)out_size; (void)ws_size;
  const float* h    = (const float*)d_in[0];
  const float* cosb = (const float*)d_in[1];
  const float* sinb = (const float*)d_in[2];
  const float* Wq   = (const float*)d_in[3];
  const float* Wk   = (const float*)d_in[4];
  const float* Wv   = (const float*)d_in[5];
  const float* Wo   = (const float*)d_in[6];
  const float* qw   = (const float*)d_in[7];
  const float* kw   = (const float*)d_in[8];
  float* out = (float*)d_out;

  // workspace layout (64MB total, lifetime-overlapped):
  //  0..16MB : h_bf16, later attn-out bf16
  // 16..20MB : K [NKV][S][HD]
  // 20..24MB : Vt [NKV][HD][S]
  // 24..36MB : Wqkv bf16 (dead after gemm1) -> 24..40MB: Q [NH][S][HD]
  // 40..64MB : qkv bf16 [S][3072] (dead after vtrans) -> 40..48MB: Wo bf16
  char* ws = (char*)d_ws;
  u16* hbf  = (u16*)(ws);
  u16* Kb   = (u16*)(ws + (16u << 20));
  u16* Vtb  = (u16*)(ws + (20u << 20));
  u16* wqkv = (u16*)(ws + (24u << 20));
  u16* Qb   = (u16*)(ws + (24u << 20));
  u16* qkvb = (u16*)(ws + (40u << 20));
  u16* wob  = (u16*)(ws + (40u << 20));

  cvt_f32_bf16<<<4096, 256, 0, stream>>>(h, hbf);                    // 8M
  cvt_f32_bf16<<<2048, 256, 0, stream>>>(Wq, wqkv);                  // 4M
  cvt_f32_bf16<<<512, 256, 0, stream>>>(Wk, wqkv + 4u * 1024 * 1024);
  cvt_f32_bf16<<<512, 256, 0, stream>>>(Wv, wqkv + 5u * 1024 * 1024);

  gemm_bt<true><<<dim3(32, 24), 256, 0, stream>>>(hbf, wqkv, qkvb, 4096, 3072, 2048);

  norm_rope<<<4096, 256, 0, stream>>>(qkvb, cosb, sinb, qw, kw, Qb, Kb);
  vtrans<<<dim3(64, 2, 4), 256, 0, stream>>>(qkvb, Vtb);

  cvt_f32_bf16<<<2048, 256, 0, stream>>>(Wo, wob);                   // qkvb dead now

  attn_fwd<<<dim3(32, 16), 256, 0, stream>>>(Qb, Kb, Vtb, hbf);      // hbf dead after gemm1

  gemm_bt<false><<<dim3(32, 16), 256, 0, stream>>>(hbf, wob, out, 4096, 2048, 2048);
}